// Round 2
// baseline (2525.096 us; speedup 1.0000x reference)
//
#include <hip/hip_runtime.h>

typedef unsigned short u16;
typedef unsigned int u32;
typedef float f32x4 __attribute__((ext_vector_type(4)));
typedef __bf16 bf16x8 __attribute__((ext_vector_type(8)));
typedef u16 u16x4 __attribute__((ext_vector_type(4)));
typedef u16 u16x8 __attribute__((ext_vector_type(8)));

// ---------- helpers ----------
__device__ __forceinline__ u16 f2bf(float f) {
  union { float f; u32 u; } x; x.f = f;
  u32 r = x.u + 0x7fffu + ((x.u >> 16) & 1u);   // RNE
  return (u16)(r >> 16);
}

__device__ __forceinline__ void gl_lds16(const void* g, void* l) {
  // async global->LDS, 16B per lane; LDS dest = wave-uniform base + lane*16
  __builtin_amdgcn_global_load_lds(
      (__attribute__((address_space(1))) void*)g,
      (__attribute__((address_space(3))) void*)l, 16, 0, 0);
}

// ---------- fp32 [K,N] -> bf16 [N,K] transpose-convert ----------
__global__ __launch_bounds__(256)
void convT_k(const float* __restrict__ in, u16* __restrict__ out, int K, int N) {
  __shared__ float tile[32][33];
  const int n0 = blockIdx.x * 32, k0 = blockIdx.y * 32;
  const size_t zoff = (size_t)blockIdx.z * K * N;
  in += zoff; out += zoff;
  const int tx = threadIdx.x, ty = threadIdx.y;   // 32 x 8
#pragma unroll
  for (int i = 0; i < 4; ++i) {
    const int k = k0 + ty * 4 + i, n = n0 + tx;
    tile[ty * 4 + i][tx] = (n < N) ? in[(size_t)k * N + n] : 0.f;
  }
  __syncthreads();
#pragma unroll
  for (int i = 0; i < 4; ++i) {
    const int n = n0 + ty * 4 + i;
    if (n < N) out[(size_t)n * K + k0 + tx] = f2bf(tile[tx][ty * 4 + i]);
  }
}

// ---------- embedding + positional ----------
__global__ __launch_bounds__(256)
void embed_k(const int* __restrict__ tokens, const float* __restrict__ emb,
             const float* __restrict__ pe, float* __restrict__ x,
             u16* __restrict__ xb) {
  const int row = blockIdx.x;        // b*2048 + s
  const int s = row & 2047;
  const int tok = tokens[row];
  const int c = threadIdx.x;         // 256 threads * float4 = 1024
  f32x4 v = *(const f32x4*)(emb + (size_t)tok * 1024 + c * 4);
  f32x4 p = *(const f32x4*)(pe + (size_t)s * 1024 + c * 4);
  v = v + p;
  *(f32x4*)(x + (size_t)row * 1024 + c * 4) = v;
  u16x4 hv;
#pragma unroll
  for (int i = 0; i < 4; ++i) hv[i] = f2bf(v[i]);
  *(u16x4*)(xb + (size_t)row * 1024 + c * 4) = hv;
}

// ---------- 128x128 bf16 GEMM, C = A[M,K] * Bt[N,K]^T  (m97 structure) ----------
// MODE 0: write bf16 C          (qkv)
// MODE 1: x = resid + C (fp32), xb = bf16(x)   (Wo + residual)
// MODE 2: write fp32 C with col<N guard        (unembed -> d_out)
template <int MODE>
__global__ __launch_bounds__(256)
void gemm_bt(const u16* __restrict__ A, const u16* __restrict__ Bt,
             u16* __restrict__ Cbf, float* __restrict__ Cf,
             const float* __restrict__ resid, float* __restrict__ xout,
             u16* __restrict__ xbout, int N, int K) {
  __shared__ u16 As[128 * 32];
  __shared__ u16 Bs[128 * 32];
  const int t = threadIdx.x;
  const int wv = t >> 6, ln = t & 63;
  const int wr = wv >> 1, wc = wv & 1;      // 2x2 waves of 64x64
  const int lr = ln & 15, lg = ln >> 4;
  const int m0 = blockIdx.y * 128, n0 = blockIdx.x * 128;

  const int srow = t >> 2, scol = (t & 3) * 8;    // staging: 64 rows/issue
  const u16* gA0 = A + (size_t)(m0 + srow) * K + scol;
  const u16* gA1 = gA0 + (size_t)64 * K;
  int br0 = n0 + srow, br1 = n0 + 64 + srow;
  if (MODE == 2) { if (br0 >= N) br0 = N - 1; if (br1 >= N) br1 = N - 1; }
  const u16* gB0 = Bt + (size_t)br0 * K + scol;
  const u16* gB1 = Bt + (size_t)br1 * K + scol;
  u16* lA = As + wv * 512;   // lane0 dst for this wave
  u16* lB = Bs + wv * 512;

  f32x4 acc[4][4] = {};

  for (int kt = 0; kt < K; kt += 32) {
    gl_lds16(gA0 + kt, lA);
    gl_lds16(gA1 + kt, lA + 2048);
    gl_lds16(gB0 + kt, lB);
    gl_lds16(gB1 + kt, lB + 2048);
    __syncthreads();
    bf16x8 af[4], bfv[4];
#pragma unroll
    for (int m = 0; m < 4; ++m)
      af[m] = *(const bf16x8*)(As + (wr * 64 + m * 16 + lr) * 32 + lg * 8);
#pragma unroll
    for (int n = 0; n < 4; ++n)
      bfv[n] = *(const bf16x8*)(Bs + (wc * 64 + n * 16 + lr) * 32 + lg * 8);
#pragma unroll
    for (int m = 0; m < 4; ++m)
#pragma unroll
      for (int n = 0; n < 4; ++n)
        acc[m][n] = __builtin_amdgcn_mfma_f32_16x16x32_bf16(af[m], bfv[n], acc[m][n], 0, 0, 0);
    __syncthreads();
  }

#pragma unroll
  for (int m = 0; m < 4; ++m) {
#pragma unroll
    for (int e = 0; e < 4; ++e) {
      const int row = m0 + wr * 64 + m * 16 + lg * 4 + e;
#pragma unroll
      for (int n = 0; n < 4; ++n) {
        const int col = n0 + wc * 64 + n * 16 + lr;
        const float v = acc[m][n][e];
        if (MODE == 0) {
          Cbf[(size_t)row * N + col] = f2bf(v);
        } else if (MODE == 1) {
          const size_t idx = (size_t)row * N + col;
          const float sv = resid[idx] + v;
          xout[idx] = sv;
          xbout[idx] = f2bf(sv);
        } else {
          if (col < N) Cf[(size_t)row * N + col] = v;
        }
      }
    }
  }
}

// ---------- causal flash attention: one block = 64 queries of one (b,h) ----------
// qkv layout [B*S, 3072]: Q at col h*64, K at 1024+h*64, V at 2048+h*64
__global__ __launch_bounds__(256)
void attn_k(const u16* __restrict__ qkv, u16* __restrict__ out) {
  __shared__ u16 Kl[64 * 64];        // [key][d], XOR-swizzled rows
  __shared__ u16 Vt[64 * 64];        // [d][key], XOR-swizzled rows
  __shared__ u16 Pl[4 * 16 * 64];    // per-wave P tile [q][key], swizzled
  const int b = blockIdx.y >> 4, h = blockIdx.y & 15;
  const int q0 = blockIdx.x * 64;
  const int t = threadIdx.x, w = t >> 6, ln = t & 63;
  const int lr = ln & 15, lg = ln >> 4;
  const u16* base = qkv + (size_t)b * 2048 * 3072 + h * 64;

  // Q fragments (16 queries per wave), held in registers for all tiles
  const int qb = q0 + w * 16;
  bf16x8 aq[2];
#pragma unroll
  for (int ki = 0; ki < 2; ++ki)
    aq[ki] = *(const bf16x8*)(base + (size_t)(qb + lr) * 3072 + ki * 32 + lg * 8);

  f32x4 o[4] = {};
  float mrow[4] = {-1e30f, -1e30f, -1e30f, -1e30f};
  float lrow[4] = {0.f, 0.f, 0.f, 0.f};

  const int skey = t >> 2;           // staging: key row per 4 threads
  const int cbs = (t & 3) * 2;       // two 16B chunks each
  char* KlB = (char*)Kl;
  char* VtB = (char*)Vt;
  char* PwB = (char*)(Pl + w * 1024);

  const int ntiles = blockIdx.x + 1; // causal: only tiles with keys <= q0+63
  for (int tt = 0; tt < ntiles; ++tt) {
    const int kb = tt * 64;
    {
      const u16* kg = base + 1024 + (size_t)(kb + skey) * 3072;
      const u16* vg = base + 2048 + (size_t)(kb + skey) * 3072;
#pragma unroll
      for (int j = 0; j < 2; ++j) {
        const int c = cbs + j;
        *(uint4*)(KlB + skey * 128 + ((c * 16) ^ ((skey & 7) << 4))) =
            *(const uint4*)(kg + c * 8);
        u16x8 vv = *(const u16x8*)(vg + c * 8);
#pragma unroll
        for (int q = 0; q < 8; ++q) {
          const int d = c * 8 + q;
          *(u16*)(VtB + d * 128 + ((skey * 2) ^ ((d & 7) << 4))) = vv[q];
        }
      }
    }
    __syncthreads();
    // S = Q K^T
    f32x4 s[4] = {};
#pragma unroll
    for (int n = 0; n < 4; ++n) {
      const int key = n * 16 + lr;
#pragma unroll
      for (int ki = 0; ki < 2; ++ki) {
        const int c = ki * 4 + lg;
        bf16x8 bk = *(const bf16x8*)(KlB + key * 128 + ((c * 16) ^ ((key & 7) << 4)));
        s[n] = __builtin_amdgcn_mfma_f32_16x16x32_bf16(aq[ki], bk, s[n], 0, 0, 0);
      }
    }
    // online softmax (rows = (lg*4+e), cols across 16 lanes)
#pragma unroll
    for (int e = 0; e < 4; ++e) {
      const int qg = qb + lg * 4 + e;
      float mx = -1e30f;
#pragma unroll
      for (int n = 0; n < 4; ++n) {
        float v = s[n][e] * 0.125f;
        v = (kb + n * 16 + lr <= qg) ? v : -1e30f;
        s[n][e] = v;
        mx = fmaxf(mx, v);
      }
#pragma unroll
      for (int d = 1; d < 16; d <<= 1) mx = fmaxf(mx, __shfl_xor(mx, d));
      const float mn = fmaxf(mrow[e], mx);
      const float sc = __expf(mrow[e] - mn);
      mrow[e] = mn;
      float ps = 0.f;
#pragma unroll
      for (int n = 0; n < 4; ++n) {
        const float p = __expf(s[n][e] - mn);
        s[n][e] = p;
        ps += p;
      }
#pragma unroll
      for (int d = 1; d < 16; d <<= 1) ps += __shfl_xor(ps, d);
      lrow[e] = lrow[e] * sc + ps;
#pragma unroll
      for (int n = 0; n < 4; ++n) o[n][e] *= sc;
    }
    // P -> per-wave LDS (C-layout scatter), then read back in A-frag layout
#pragma unroll
    for (int e = 0; e < 4; ++e) {
      const int prow = lg * 4 + e;
#pragma unroll
      for (int n = 0; n < 4; ++n) {
        const int pcol = n * 16 + lr;
        *(u16*)(PwB + prow * 128 + ((pcol * 2) ^ ((prow & 7) << 4))) = f2bf(s[n][e]);
      }
    }
    asm volatile("s_waitcnt lgkmcnt(0)" ::: "memory");
    bf16x8 ap[2];
#pragma unroll
    for (int ki = 0; ki < 2; ++ki) {
      const int c = ki * 4 + lg;
      ap[ki] = *(const bf16x8*)(PwB + lr * 128 + ((c * 16) ^ ((lr & 7) << 4)));
    }
    // O += P V
#pragma unroll
    for (int n = 0; n < 4; ++n) {
      const int d = n * 16 + lr;
#pragma unroll
      for (int ki = 0; ki < 2; ++ki) {
        const int c = ki * 4 + lg;
        bf16x8 bv = *(const bf16x8*)(VtB + d * 128 + ((c * 16) ^ ((d & 7) << 4)));
        o[n] = __builtin_amdgcn_mfma_f32_16x16x32_bf16(ap[ki], bv, o[n], 0, 0, 0);
      }
    }
    __syncthreads();   // protect Kl/Vt before next tile's staging
  }
  // normalize + write [B,S,D] bf16
#pragma unroll
  for (int e = 0; e < 4; ++e) {
    const int qg = qb + lg * 4 + e;
    const float inv = 1.f / lrow[e];
#pragma unroll
    for (int n = 0; n < 4; ++n)
      out[(size_t)(b * 2048 + qg) * 1024 + h * 64 + n * 16 + lr] = f2bf(o[n][e] * inv);
  }
}

// ---------- launch ----------
extern "C" void kernel_launch(void* const* d_in, const int* in_sizes, int n_in,
                              void* d_out, int out_size, void* d_ws, size_t ws_size,
                              hipStream_t stream) {
  (void)in_sizes; (void)n_in; (void)out_size; (void)ws_size;
  const int*   tokens  = (const int*)d_in[0];
  const float* tok_emb = (const float*)d_in[1];
  const float* W_qkv   = (const float*)d_in[2];
  const float* W_o     = (const float*)d_in[3];
  const float* W_un    = (const float*)d_in[4];
  const float* pe      = (const float*)d_in[5];
  float* logits = (float*)d_out;

  char* ws = (char*)d_ws;
  float* x     = (float*)ws;  ws += 16777216;   // [4096,1024] fp32 residual
  u16* xb      = (u16*)ws;    ws += 8388608;    // bf16 copy
  u16* qkv     = (u16*)ws;    ws += 25165824;   // [4096,3072] bf16
  u16* attnout = (u16*)ws;    ws += 8388608;    // [4096,1024] bf16
  u16* Wqkvt   = (u16*)ws;    ws += 25165824;   // [4][3072,1024] bf16
  u16* Wot     = (u16*)ws;    ws += 8388608;    // [4][1024,1024] bf16
  u16* Wunt    = (u16*)ws;                      // [50257,1024] bf16

  // weight conversions (transposed to [N,K] for B^T GEMM operand)
  convT_k<<<dim3(96, 32, 4), dim3(32, 8), 0, stream>>>(W_qkv, Wqkvt, 1024, 3072);
  convT_k<<<dim3(32, 32, 4), dim3(32, 8), 0, stream>>>(W_o, Wot, 1024, 1024);
  convT_k<<<dim3(1571, 32, 1), dim3(32, 8), 0, stream>>>(W_un, Wunt, 1024, 50257);
  embed_k<<<dim3(4096), dim3(256), 0, stream>>>(tokens, tok_emb, pe, x, xb);

  for (int l = 0; l < 4; ++l) {
    gemm_bt<0><<<dim3(24, 32), dim3(256), 0, stream>>>(
        xb, Wqkvt + (size_t)l * 3072 * 1024, qkv, nullptr, nullptr, nullptr, nullptr, 3072, 1024);
    attn_k<<<dim3(32, 32), dim3(256), 0, stream>>>(qkv, attnout);
    gemm_bt<1><<<dim3(8, 32), dim3(256), 0, stream>>>(
        attnout, Wot + (size_t)l * 1024 * 1024, nullptr, nullptr, x, x, xb, 1024, 1024);
  }
  gemm_bt<2><<<dim3(393, 32), dim3(256), 0, stream>>>(
      xb, Wunt, nullptr, logits, nullptr, nullptr, nullptr, 50257, 1024);
}